// Round 1
// baseline (36.792 us; speedup 1.0000x reference)
//
#include <hip/hip_runtime.h>
#include <math.h>

// LDPC BP decode, fixed (3x7) H:
//   row0: vars {0,2,4,6}
//   row1: vars {1,2,5,6}
//   row2: vars {3,4,5,6}
// One thread per batch element; 5 iterations; everything in registers.
// Faithful f32 port of the JAX reference: phi(x) = logf(|tanhf(0.5x)|),
// sign algebra done exactly (sign-bit XOR, no divisions), same add order.

__device__ __forceinline__ float phi_ref(float x) {
    return logf(fabsf(tanhf(0.5f * x)));
}

// One check-row update: given 4 incoming v->c messages m[4], produce c->v c[4].
__device__ __forceinline__ void row_update(const float* m, float* c) {
    float lu0 = phi_ref(m[0]);
    float lu1 = phi_ref(m[1]);
    float lu2 = phi_ref(m[2]);
    float lu3 = phi_ref(m[3]);
    // reference: sum over the row in variable-index order (zeros at H==0 are exact identities)
    float sum = ((lu0 + lu1) + lu2) + lu3;

    unsigned s0 = __float_as_uint(m[0]) & 0x80000000u;
    unsigned s1 = __float_as_uint(m[1]) & 0x80000000u;
    unsigned s2 = __float_as_uint(m[2]) & 0x80000000u;
    unsigned s3 = __float_as_uint(m[3]) & 0x80000000u;
    unsigned par = s0 ^ s1 ^ s2 ^ s3;  // product of signs (all assumed nonzero)

    // c2v_k = -phi(sum - lu_k) * (prod signs / sign_k)  ; sign ratio == XOR of bits
    {
        float mag = -phi_ref(sum - lu0);           // phi <= 0 so mag >= 0 (or -0.0)
        c[0] = __uint_as_float(__float_as_uint(mag) ^ (par ^ s0));
    }
    {
        float mag = -phi_ref(sum - lu1);
        c[1] = __uint_as_float(__float_as_uint(mag) ^ (par ^ s1));
    }
    {
        float mag = -phi_ref(sum - lu2);
        c[2] = __uint_as_float(__float_as_uint(mag) ^ (par ^ s2));
    }
    {
        float mag = -phi_ref(sum - lu3);
        c[3] = __uint_as_float(__float_as_uint(mag) ^ (par ^ s3));
    }
}

__global__ __launch_bounds__(256) void ldpc_bp_kernel(
        const float* __restrict__ llr,
        const int*   __restrict__ iters_p,
        float*       __restrict__ out,
        int B) {
    int b = blockIdx.x * blockDim.x + threadIdx.x;
    if (b >= B) return;
    const int iters = iters_p[0];

    const float* Lp = llr + (size_t)b * 7;
    float L[7], tot[7];
#pragma unroll
    for (int j = 0; j < 7; ++j) { L[j] = Lp[j]; tot[j] = L[j]; }

    // v->c messages per row (init = H * llr at the 12 edges)
    float m0[4] = {L[0], L[2], L[4], L[6]};
    float m1[4] = {L[1], L[2], L[5], L[6]};
    float m2[4] = {L[3], L[4], L[5], L[6]};

    for (int it = 0; it < iters; ++it) {
        float c0[4], c1[4], c2[4];
        row_update(m0, c0);
        row_update(m1, c1);
        row_update(m2, c2);

        // new_llr = llr + sum over rows (axis=1) in row order r=0,1,2
        tot[0] = L[0] + c0[0];
        tot[1] = L[1] + c1[0];
        tot[2] = (L[2] + c0[1]) + c1[1];
        tot[3] = L[3] + c2[0];
        tot[4] = (L[4] + c0[2]) + c2[1];
        tot[5] = (L[5] + c1[2]) + c2[2];
        tot[6] = ((L[6] + c0[3]) + c1[3]) + c2[3];

        // new_msgs = H*new_llr - c2v  (extrinsic)
        m0[0] = tot[0] - c0[0];
        m0[1] = tot[2] - c0[1];
        m0[2] = tot[4] - c0[2];
        m0[3] = tot[6] - c0[3];
        m1[0] = tot[1] - c1[0];
        m1[1] = tot[2] - c1[1];
        m1[2] = tot[5] - c1[2];
        m1[3] = tot[6] - c1[3];
        m2[0] = tot[3] - c2[0];
        m2[1] = tot[4] - c2[1];
        m2[2] = tot[5] - c2[2];
        m2[3] = tot[6] - c2[3];
    }

    float* Op = out + (size_t)b * 7;
#pragma unroll
    for (int j = 0; j < 7; ++j) Op[j] = tot[j];
}

extern "C" void kernel_launch(void* const* d_in, const int* in_sizes, int n_in,
                              void* d_out, int out_size, void* d_ws, size_t ws_size,
                              hipStream_t stream) {
    (void)n_in; (void)d_ws; (void)ws_size;
    const float* llr  = (const float*)d_in[0];
    const int*   mi   = (const int*)d_in[1];
    float*       out  = (float*)d_out;
    const int B = in_sizes[0] / 7;           // [B,1,7] flat
    const int block = 256;
    const int grid = (B + block - 1) / block;
    ldpc_bp_kernel<<<grid, block, 0, stream>>>(llr, mi, out, B);
}

// Round 3
// 23.250 us; speedup vs baseline: 1.5825x; 1.5825x over previous
//
#include <hip/hip_runtime.h>
#include <math.h>

// LDPC BP decode, fixed (3x7) H:
//   row0: vars {0,2,4,6}
//   row1: vars {1,2,5,6}
//   row2: vars {3,4,5,6}
// One thread per batch element; iterations fully in registers.
//
// phi(x) = log|tanh(x/2)| computed directly via hardware exp2/log2:
//   stage 1 (v->c magnitude, log2 domain):
//       t = exp2(-a*log2e); w = 1 - 2*t/(1+t)   (w == f32-rounded tanh(a/2))
//       lu2 = log2(w)  (<= 0)
//   stage 2 (c->v magnitude, natural units):
//       t' = exp2(S2)  (S2 = sum of other lu2's, <= 0 -- no base conversion)
//       om = (x < 0.25) ? expm1-poly(x) : 1 - t'      (x = -S2*ln2)
//       M  = ln2 * (log2(1+t') - log2(om))            (>= 0)
// Signs tracked exactly via sign-bit XOR (no divisions on the sign path).

#define LOG2E 1.4426950408889634f
#define LN2   0.6931471805599453f

__device__ __forceinline__ float rcp_nr(float d) {
    float r = __builtin_amdgcn_rcpf(d);
    // one Newton step: r = r*(2 - d*r)
    float e = __builtin_fmaf(-d, r, 2.0f);
    return r * e;
}

// log2|tanh(a/2)| for a >= 0 (returns <= 0)
__device__ __forceinline__ float lu2_of(float a) {
    float t   = __builtin_amdgcn_exp2f(-a * LOG2E);
    float den = 1.0f + t;
    float q   = t * rcp_nr(den);              // t/(1+t), ~1 ulp
    float w   = __builtin_fmaf(-2.0f, q, 1.0f);   // tanh(a/2), f32-grid
    w = fabsf(w);                              // guard tiny negative from rounding
    return __builtin_amdgcn_logf(w);           // v_log_f32 = log2
}

// c->v magnitude from S2 = log2-domain extrinsic sum (<= 0); returns >= 0
__device__ __forceinline__ float mag_of(float S2) {
    float tp = __builtin_amdgcn_exp2f(S2);     // e^{-|S|} = 2^{S2}
    float x  = -S2 * LN2;                      // |S| natural
    // om = -expm1(-x): poly for small x (avoids 1-t cancellation), direct else
    float p  = __builtin_fmaf(-0.25f, x, 1.0f);
    p = __builtin_fmaf(-0.3333333333333f * x, p, 1.0f);
    p = __builtin_fmaf(-0.5f * x, p, 1.0f);
    float om_poly = x * p;                     // x - x^2/2 + x^3/6 - x^4/24
    float om_dir  = 1.0f - tp;
    float om  = (x < 0.25f) ? om_poly : om_dir;
    float den = 1.0f + tp;
    return LN2 * (__builtin_amdgcn_logf(den) - __builtin_amdgcn_logf(om));
}

// One check-row update: 4 signed v->c messages m[4] -> signed c->v c[4]
__device__ __forceinline__ void row_update(const float* m, float* c) {
    unsigned s0 = __float_as_uint(m[0]) & 0x80000000u;
    unsigned s1 = __float_as_uint(m[1]) & 0x80000000u;
    unsigned s2 = __float_as_uint(m[2]) & 0x80000000u;
    unsigned s3 = __float_as_uint(m[3]) & 0x80000000u;
    unsigned par = s0 ^ s1 ^ s2 ^ s3;

    float l0 = lu2_of(fabsf(m[0]));
    float l1 = lu2_of(fabsf(m[1]));
    float l2 = lu2_of(fabsf(m[2]));
    float l3 = lu2_of(fabsf(m[3]));
    float sum = ((l0 + l1) + l2) + l3;        // same order as reference row-sum

    float M0 = mag_of(sum - l0);
    float M1 = mag_of(sum - l1);
    float M2 = mag_of(sum - l2);
    float M3 = mag_of(sum - l3);

    c[0] = __uint_as_float(__float_as_uint(M0) ^ (par ^ s0));
    c[1] = __uint_as_float(__float_as_uint(M1) ^ (par ^ s1));
    c[2] = __uint_as_float(__float_as_uint(M2) ^ (par ^ s2));
    c[3] = __uint_as_float(__float_as_uint(M3) ^ (par ^ s3));
}

__global__ __launch_bounds__(256) void ldpc_bp_kernel(
        const float* __restrict__ llr,
        const int*   __restrict__ iters_p,
        float*       __restrict__ out,
        int B) {
    int b = blockIdx.x * blockDim.x + threadIdx.x;
    if (b >= B) return;
    const int iters = iters_p[0];

    const float* Lp = llr + (size_t)b * 7;
    float L[7], tot[7];
#pragma unroll
    for (int j = 0; j < 7; ++j) { L[j] = Lp[j]; tot[j] = L[j]; }

    float m0[4] = {L[0], L[2], L[4], L[6]};
    float m1[4] = {L[1], L[2], L[5], L[6]};
    float m2[4] = {L[3], L[4], L[5], L[6]};

    for (int it = 0; it < iters; ++it) {
        float c0[4], c1[4], c2[4];
        row_update(m0, c0);
        row_update(m1, c1);
        row_update(m2, c2);

        tot[0] = L[0] + c0[0];
        tot[1] = L[1] + c1[0];
        tot[2] = (L[2] + c0[1]) + c1[1];
        tot[3] = L[3] + c2[0];
        tot[4] = (L[4] + c0[2]) + c2[1];
        tot[5] = (L[5] + c1[2]) + c2[2];
        tot[6] = ((L[6] + c0[3]) + c1[3]) + c2[3];

        m0[0] = tot[0] - c0[0];
        m0[1] = tot[2] - c0[1];
        m0[2] = tot[4] - c0[2];
        m0[3] = tot[6] - c0[3];
        m1[0] = tot[1] - c1[0];
        m1[1] = tot[2] - c1[1];
        m1[2] = tot[5] - c1[2];
        m1[3] = tot[6] - c1[3];
        m2[0] = tot[3] - c2[0];
        m2[1] = tot[4] - c2[1];
        m2[2] = tot[5] - c2[2];
        m2[3] = tot[6] - c2[3];
    }

    float* Op = out + (size_t)b * 7;
#pragma unroll
    for (int j = 0; j < 7; ++j) Op[j] = tot[j];
}

extern "C" void kernel_launch(void* const* d_in, const int* in_sizes, int n_in,
                              void* d_out, int out_size, void* d_ws, size_t ws_size,
                              hipStream_t stream) {
    (void)n_in; (void)d_ws; (void)ws_size;
    const float* llr  = (const float*)d_in[0];
    const int*   mi   = (const int*)d_in[1];
    float*       out  = (float*)d_out;
    const int B = in_sizes[0] / 7;
    const int block = 256;
    const int grid = (B + block - 1) / block;
    ldpc_bp_kernel<<<grid, block, 0, stream>>>(llr, mi, out, B);
}

// Round 4
// 14.724 us; speedup vs baseline: 2.4988x; 1.5791x over previous
//
#include <hip/hip_runtime.h>
#include <math.h>

// LDPC BP decode, fixed (3x7) H:
//   row0: vars {0,2,4,6}
//   row1: vars {1,2,5,6}
//   row2: vars {3,4,5,6}
// One thread per batch element; iterations fully in registers, fully unrolled.
//
// Check node via signed tanh-product (mathematically == the reference's
// phi-sum): p_j = tanh(m_j/2);  c_k = 2*atanh( prod_{j!=k} p_j ).
// Everything runs in log2-domain LLR units (m2 = m/ln2):
//   t   = exp2(-|m2|)                     (== e^{-|m|}, one v_exp_f32)
//   q   = t * rcp_nr(1+t)
//   p   = sign(m) * fma(-2, q, 1)         (== f32-rounded tanh(|m|/2) --
//                                          keeps numpy's 2^-24 quantization
//                                          grid near saturation; direct
//                                          (1-t)/(1+t) would mis-grid by 2x)
//   y_k = prod of other p's               (fwd/bwd partials, 6 muls)
//   c2  = log2(1+y) - log2(1-y)           (== c/ln2; 1-y is Sterbenz-exact
//                                          near saturation so the k-quanta
//                                          match the reference's summed logs)
// Load: L2 = llr * log2e.  Store: out = tot2 * ln2.

#define LOG2E 1.4426950408889634f
#define LN2   0.6931471805599453f

__device__ __forceinline__ float rcp_nr(float d) {
    float r = __builtin_amdgcn_rcpf(d);
    float e = __builtin_fmaf(-d, r, 2.0f);   // one Newton step
    return r * e;
}

// signed f32-grid tanh(m2*ln2/2) from a log2-domain message
__device__ __forceinline__ float p_of(float m2) {
    float t  = __builtin_amdgcn_exp2f(-fabsf(m2));
    float q  = t * rcp_nr(1.0f + t);                 // t/(1+t) in [0, 0.5]
    float pm = __builtin_fmaf(-2.0f, q, 1.0f);       // |tanh|, matches numpy grid
    unsigned s = __float_as_uint(m2) & 0x80000000u;
    return __uint_as_float(__float_as_uint(pm) | s);
}

// one check row: 4 v->c messages (log2 units) -> 4 extrinsic c->v (log2 units)
__device__ __forceinline__ void row_update(const float* m, float* c) {
    float p0 = p_of(m[0]);
    float p1 = p_of(m[1]);
    float p2 = p_of(m[2]);
    float p3 = p_of(m[3]);

    float f01 = p0 * p1;
    float b23 = p2 * p3;
    float y0 = p1 * b23;
    float y1 = p0 * b23;
    float y2 = f01 * p3;
    float y3 = f01 * p2;

    c[0] = __builtin_amdgcn_logf(1.0f + y0) - __builtin_amdgcn_logf(1.0f - y0);
    c[1] = __builtin_amdgcn_logf(1.0f + y1) - __builtin_amdgcn_logf(1.0f - y1);
    c[2] = __builtin_amdgcn_logf(1.0f + y2) - __builtin_amdgcn_logf(1.0f - y2);
    c[3] = __builtin_amdgcn_logf(1.0f + y3) - __builtin_amdgcn_logf(1.0f - y3);
}

// full decode in log2 units; iters constant-folds at the iters==5 call site
__device__ __forceinline__ void decode(int iters, const float* L, float* tot) {
    float m0[4] = {L[0], L[2], L[4], L[6]};
    float m1[4] = {L[1], L[2], L[5], L[6]};
    float m2[4] = {L[3], L[4], L[5], L[6]};

    for (int it = 0; it < iters; ++it) {
        float c0[4], c1[4], c2[4];
        row_update(m0, c0);
        row_update(m1, c1);
        row_update(m2, c2);

        tot[0] = L[0] + c0[0];
        tot[1] = L[1] + c1[0];
        tot[2] = (L[2] + c0[1]) + c1[1];
        tot[3] = L[3] + c2[0];
        tot[4] = (L[4] + c0[2]) + c2[1];
        tot[5] = (L[5] + c1[2]) + c2[2];
        tot[6] = ((L[6] + c0[3]) + c1[3]) + c2[3];

        m0[0] = tot[0] - c0[0];
        m0[1] = tot[2] - c0[1];
        m0[2] = tot[4] - c0[2];
        m0[3] = tot[6] - c0[3];
        m1[0] = tot[1] - c1[0];
        m1[1] = tot[2] - c1[1];
        m1[2] = tot[5] - c1[2];
        m1[3] = tot[6] - c1[3];
        m2[0] = tot[3] - c2[0];
        m2[1] = tot[4] - c2[1];
        m2[2] = tot[5] - c2[2];
        m2[3] = tot[6] - c2[3];
    }
}

__global__ __launch_bounds__(256) void ldpc_bp_kernel(
        const float* __restrict__ llr,
        const int*   __restrict__ iters_p,
        float*       __restrict__ out,
        int B) {
    int b = blockIdx.x * blockDim.x + threadIdx.x;
    if (b >= B) return;
    const int iters = iters_p[0];

    const float* Lp = llr + (size_t)b * 7;
    float L2[7], tot2[7];
#pragma unroll
    for (int j = 0; j < 7; ++j) {
        L2[j] = Lp[j] * LOG2E;   // -> log2-domain LLR units
        tot2[j] = L2[j];
    }

    if (iters == 5) {
        decode(5, L2, tot2);     // constant trip count -> fully unrolled
    } else {
        decode(iters, L2, tot2);
    }

    float* Op = out + (size_t)b * 7;
#pragma unroll
    for (int j = 0; j < 7; ++j) Op[j] = tot2[j] * LN2;
}

extern "C" void kernel_launch(void* const* d_in, const int* in_sizes, int n_in,
                              void* d_out, int out_size, void* d_ws, size_t ws_size,
                              hipStream_t stream) {
    (void)n_in; (void)d_ws; (void)ws_size;
    const float* llr  = (const float*)d_in[0];
    const int*   mi   = (const int*)d_in[1];
    float*       out  = (float*)d_out;
    const int B = in_sizes[0] / 7;
    const int block = 256;
    const int grid = (B + block - 1) / block;
    ldpc_bp_kernel<<<grid, block, 0, stream>>>(llr, mi, out, B);
}